// Round 3
// baseline (120.662 us; speedup 1.0000x reference)
//
#include <hip/hip_runtime.h>
#include <hip/hip_bf16.h>

// NT-Xent loss, BS=4096, D=256, TAU=0.5.
// R3: LDS-free Gram kernel. knorm writes zn in MFMA-fragment-native swizzled
// layout; kgemm assigns one wave per 64x64 triangular tile and loads A/B
// fragments straight from global (perfectly coalesced 1KB per load) -- no
// LDS, no barriers, fully independent waves. Row+col sums by symmetry.
//
// zn_sw layout: chunk (rg, kb) = rows rg*16..+15, k kb*32..+31, stored as
// 64 lanes x 16B at byte offset (rg*8+kb)*1024 + lane*16, where lane l
// holds row rg*16+(l&15), k = kb*32+(l>>4)*8 + j (j=0..7). This is exactly
// the mfma_f32_16x16x32_bf16 A/B fragment layout.

#define N_ROWS 8192
#define BSZ    4096
#define DIM    256
#define INV_TAU 2.0f
#define EPS_REF 1e-8f
#define COS_EPS 1e-8f
#define NG      128                    // 64-row groups
#define NTT     (NG * (NG + 1) / 2)    // 8256 triangular wave-tiles
#define NBLK    (NTT / 4)              // 2064 blocks of 4 waves

typedef __attribute__((ext_vector_type(8))) __bf16 bf16x8;
typedef __attribute__((ext_vector_type(4))) float  f32x4;

// ---------------- Kernel 1: normalize + swizzle to fragment layout ----------
__global__ __launch_bounds__(256) void knorm(const float* __restrict__ zi,
                                             const float* __restrict__ zj,
                                             __hip_bfloat16* __restrict__ znsw) {
    const int row = blockIdx.x * 4 + (threadIdx.x >> 6);
    const int l   = threadIdx.x & 63;
    const float* src = (row < BSZ) ? (zi + (size_t)row * DIM)
                                   : (zj + (size_t)(row - BSZ) * DIM);
    float4 v = ((const float4*)src)[l];                 // k = 4l .. 4l+3
    float ss = v.x*v.x + v.y*v.y + v.z*v.z + v.w*v.w;
    #pragma unroll
    for (int off = 32; off >= 1; off >>= 1) ss += __shfl_xor(ss, off);
    const float inv = 1.0f / fmaxf(sqrtf(ss), COS_EPS);
    union { ushort4 u; __hip_bfloat16 h[4]; } o;
    o.h[0] = __float2bfloat16(v.x * inv);
    o.h[1] = __float2bfloat16(v.y * inv);
    o.h[2] = __float2bfloat16(v.z * inv);
    o.h[3] = __float2bfloat16(v.w * inv);
    // dest: rg=row>>4, kb=l>>3, frag-lane fl=(row&15)+((l>>1)&3)*16, half=l&1
    const int rg = row >> 4, kb = l >> 3;
    const int fl = (row & 15) + ((l >> 1) & 3) * 16;
    char* dst = (char*)znsw + ((size_t)(rg * 8 + kb) * 64 + fl) * 16 + (l & 1) * 8;
    *(ushort4*)dst = o.u;
}

// ---------------- Kernel 2: triangular Gram, direct-load MFMA ---------------
// P[s][r] = sum_{c in 64-col strip s} exp(sim[r][c]/tau).
// Tile (gi,gj), gi<=gj: row sums -> P[gj][gi*64+..]; col sums (gi<gj) ->
// P[gi][gj*64+..]. gi==gj diag -> selfdot; gj==gi+64 diag -> pairdot.
__global__ __launch_bounds__(256) void kgemm(const __hip_bfloat16* __restrict__ znsw,
                                             float* __restrict__ P,
                                             float* __restrict__ selfdot,
                                             float* __restrict__ pairdot) {
    const int w = threadIdx.x >> 6;
    const int l = threadIdx.x & 63;
    const int t = blockIdx.x * 4 + w;

    // triangular decode: S(g) = g*(257-g)/2 <= t < S(g+1)
    int gi = (int)((257.0f - sqrtf(66049.0f - 8.0f * (float)t)) * 0.5f);
    while ((gi + 1) * (257 - (gi + 1)) / 2 <= t) ++gi;
    while (gi * (257 - gi) / 2 > t) --gi;
    const int gj = gi + (t - gi * (257 - gi) / 2);

    const char* base = (const char*)znsw;
    const char* abase = base + (size_t)(gi * 4) * 8192 + l * 16;  // +mt*8192+kb*1024
    const char* bbase = base + (size_t)(gj * 4) * 8192 + l * 16;

    f32x4 acc[4][4];
    #pragma unroll
    for (int mt = 0; mt < 4; ++mt)
        #pragma unroll
        for (int nt = 0; nt < 4; ++nt)
            acc[mt][nt] = (f32x4){0.f, 0.f, 0.f, 0.f};

    bf16x8 af[2][4], bf[2][4];
    #pragma unroll
    for (int mt = 0; mt < 4; ++mt) {
        af[0][mt] = *(const bf16x8*)(abase + mt * 8192);
        bf[0][mt] = *(const bf16x8*)(bbase + mt * 8192);
    }
    #pragma unroll
    for (int kb = 0; kb < 8; ++kb) {
        const int cur = kb & 1, nxt = cur ^ 1;
        if (kb < 7) {
            #pragma unroll
            for (int mt = 0; mt < 4; ++mt) {
                af[nxt][mt] = *(const bf16x8*)(abase + mt * 8192 + (kb + 1) * 1024);
                bf[nxt][mt] = *(const bf16x8*)(bbase + mt * 8192 + (kb + 1) * 1024);
            }
        }
        #pragma unroll
        for (int mt = 0; mt < 4; ++mt)
            #pragma unroll
            for (int nt = 0; nt < 4; ++nt)
                acc[mt][nt] = __builtin_amdgcn_mfma_f32_16x16x32_bf16(
                    af[cur][mt], bf[cur][nt], acc[mt][nt], 0, 0, 0);
    }

    // ---- wave-local epilogue ----
    // C/D layout: local col = l&15, local row = (l>>4)*4 + reg.
    const int c = l & 15, q = l >> 4;
    const int rsel = c - 4 * q;                 // diag reg if in [0,4)
    const bool vld = (rsel >= 0) && (rsel < 4);

    // diagonal raw dots (pre-exp) from acc[mt][mt]
    if (gi == gj || gj == gi + 64) {
        float dv[4];
        #pragma unroll
        for (int mt = 0; mt < 4; ++mt) {
            float d = acc[mt][mt][0];
            #pragma unroll
            for (int r = 1; r < 4; ++r)
                if (rsel == r) d = acc[mt][mt][r];
            dv[mt] = d;
        }
        if (vld) {
            float* dst = (gi == gj) ? selfdot : pairdot;
            #pragma unroll
            for (int mt = 0; mt < 4; ++mt)
                dst[gi * 64 + mt * 16 + c] = dv[mt];
        }
    }

    // exp in place
    #pragma unroll
    for (int mt = 0; mt < 4; ++mt)
        #pragma unroll
        for (int nt = 0; nt < 4; ++nt)
            #pragma unroll
            for (int r = 0; r < 4; ++r)
                acc[mt][nt][r] = __expf(acc[mt][nt][r] * INV_TAU);

    // row sums: sum over nt (cols of this tile), reduce over col lanes
    float rs[4][4];
    #pragma unroll
    for (int mt = 0; mt < 4; ++mt)
        #pragma unroll
        for (int r = 0; r < 4; ++r) {
            float s = acc[mt][0][r] + acc[mt][1][r] + acc[mt][2][r] + acc[mt][3][r];
            rs[mt][r] = s;
        }
    #pragma unroll
    for (int off = 1; off <= 8; off <<= 1)
        #pragma unroll
        for (int mt = 0; mt < 4; ++mt)
            #pragma unroll
            for (int r = 0; r < 4; ++r)
                rs[mt][r] += __shfl_xor(rs[mt][r], off);
    if (c == 0) {
        #pragma unroll
        for (int mt = 0; mt < 4; ++mt) {
            float4 o4 = make_float4(rs[mt][0], rs[mt][1], rs[mt][2], rs[mt][3]);
            *(float4*)&P[(size_t)gj * N_ROWS + gi * 64 + mt * 16 + q * 4] = o4;
        }
    }

    // col sums (strictly-upper tiles): sum over mt,reg, reduce over quad lanes
    if (gi != gj) {
        float cs[4];
        #pragma unroll
        for (int nt = 0; nt < 4; ++nt) {
            float s = 0.f;
            #pragma unroll
            for (int mt = 0; mt < 4; ++mt)
                #pragma unroll
                for (int r = 0; r < 4; ++r)
                    s += acc[mt][nt][r];
            s += __shfl_xor(s, 16);
            s += __shfl_xor(s, 32);
            cs[nt] = s;
        }
        if (q == 0) {
            #pragma unroll
            for (int nt = 0; nt < 4; ++nt)
                P[(size_t)gi * N_ROWS + gj * 64 + nt * 16 + c] = cs[nt];
        }
    }
}

// ---------------- Kernel 3: per-row loss, atomic mean -----------------------
__global__ __launch_bounds__(256) void kfinal(const float* __restrict__ P,
                                              const float* __restrict__ selfdot,
                                              const float* __restrict__ pairdot,
                                              float* __restrict__ out) {
    const int i = blockIdx.x * 256 + threadIdx.x;
    float s = 0.f;
    #pragma unroll
    for (int st = 0; st < NG; ++st)
        s += P[(size_t)st * N_ROWS + i];
    const float selfe = __expf(selfdot[i] * INV_TAU);
    const float pd    = pairdot[(i < BSZ) ? i : i - BSZ];
    float loss = logf(s - selfe + EPS_REF) - pd * INV_TAU;
    #pragma unroll
    for (int off = 32; off >= 1; off >>= 1) loss += __shfl_xor(loss, off);
    __shared__ float wsum[4];
    if ((threadIdx.x & 63) == 0) wsum[threadIdx.x >> 6] = loss;
    __syncthreads();
    if (threadIdx.x == 0)
        atomicAdd(out, (wsum[0] + wsum[1] + wsum[2] + wsum[3]) * (1.0f / (float)N_ROWS));
}

extern "C" void kernel_launch(void* const* d_in, const int* in_sizes, int n_in,
                              void* d_out, int out_size, void* d_ws, size_t ws_size,
                              hipStream_t stream) {
    const float* zi = (const float*)d_in[0];
    const float* zj = (const float*)d_in[1];
    float* out = (float*)d_out;

    char* ws = (char*)d_ws;
    __hip_bfloat16* znsw = (__hip_bfloat16*)ws;                     // 4 MB
    float* P       = (float*)(ws + 4 * 1024 * 1024);                // 4 MB
    float* selfdot = (float*)(ws + 8 * 1024 * 1024);                // 32 KB
    float* pairdot = (float*)(ws + 8 * 1024 * 1024 + 32 * 1024);    // 16 KB

    hipMemsetAsync(out, 0, sizeof(float), stream);
    knorm <<<N_ROWS / 4, 256, 0, stream>>>(zi, zj, znsw);
    kgemm <<<NBLK, 256, 0, stream>>>(znsw, P, selfdot, pairdot);
    kfinal<<<N_ROWS / 256, 256, 0, stream>>>(P, selfdot, pairdot, out);
}